// Round 3
// baseline (135.585 us; speedup 1.0000x reference)
//
#include <hip/hip_runtime.h>

using bf16x8 = __attribute__((ext_vector_type(8))) short;
using f32x4  = __attribute__((ext_vector_type(4))) float;

#define DEVI __device__ __forceinline__

// round-to-nearest-even fp32 -> bf16 (bit pattern)
DEVI unsigned short f2bf(float f) {
  union { float ff; unsigned u; } v; v.ff = f;
  unsigned r = v.u + 0x7FFFu + ((v.u >> 16) & 1u);
  return (unsigned short)(r >> 16);
}

// async global->LDS, 16B per lane; l must be wave-uniform base (HW adds lane*16)
DEVI void g2l16(const void* g, void* l) {
  __builtin_amdgcn_global_load_lds(
      (const __attribute__((address_space(1))) unsigned int*)g,
      (__attribute__((address_space(3))) unsigned int*)l, 16, 0, 0);
}

// ---------------- x fp32 -> bf16 ----------------
__global__ void k_convx(const float* __restrict__ in, unsigned short* __restrict__ out, int n4) {
  int i = blockIdx.x * 256 + threadIdx.x;
  if (i >= n4) return;
  float4 v = reinterpret_cast<const float4*>(in)[i];
  ushort4 o;
  o.x = f2bf(v.x); o.y = f2bf(v.y); o.z = f2bf(v.z); o.w = f2bf(v.w);
  reinterpret_cast<ushort4*>(out)[i] = o;
}

// ---------------- transpose+convert: out[c][r] = bf16(in[r][c]) ----------------
__global__ void k_tconv(const float* __restrict__ in, unsigned short* __restrict__ out, int R, int C) {
  __shared__ float tile[32][33];
  int c0 = blockIdx.x * 32, r0 = blockIdx.y * 32;
  int x = threadIdx.x, y = threadIdx.y;  // block (32,8)
  for (int i = y; i < 32; i += 8) tile[i][x] = in[(size_t)(r0 + i) * C + c0 + x];
  __syncthreads();
  for (int i = y; i < 32; i += 8) out[(size_t)(c0 + i) * R + r0 + x] = f2bf(tile[x][i]);
}

// ---------------- QKV GEMM: [2048,1024] x [3072,1024]^T, epilogue scatters q/k/vT ----------------
__global__ __launch_bounds__(256) void k_gemm_qkv(
    const unsigned short* __restrict__ A, const unsigned short* __restrict__ Bt,
    const float* __restrict__ bias,
    unsigned short* __restrict__ qs, unsigned short* __restrict__ kbuf,
    unsigned short* __restrict__ vT) {
  constexpr int K = 1024;
  __shared__ __align__(16) unsigned short As[128 * 64];
  __shared__ __align__(16) unsigned short Bs[128 * 64];
  const int lane = threadIdx.x & 63, wid = threadIdx.x >> 6;
  const int m0 = blockIdx.y * 128, n0 = blockIdx.x * 128;
  const int wr = (wid >> 1) * 64, wc = (wid & 1) * 64;
  const int g = lane >> 4, li = lane & 15;
  f32x4 acc[4][4] = {};
  for (int k0 = 0; k0 < K; k0 += 64) {
    __syncthreads();
    for (int c = wid; c < 16; c += 4) {
      const int fb = c * 1024;
      const int flat = fb + lane * 16;
      const int row = flat >> 7, colb = flat & 127;
      g2l16((const char*)A  + ((size_t)(m0 + row) * K + k0) * 2 + colb, (char*)As + fb);
      g2l16((const char*)Bt + ((size_t)(n0 + row) * K + k0) * 2 + colb, (char*)Bs + fb);
    }
    __syncthreads();
#pragma unroll
    for (int ks = 0; ks < 2; ks++) {
      const int kk = ks * 32 + g * 8;
      bf16x8 a[4], b[4];
#pragma unroll
      for (int i = 0; i < 4; i++)
        a[i] = *reinterpret_cast<const bf16x8*>(As + (wr + i * 16 + li) * 64 + kk);
#pragma unroll
      for (int j = 0; j < 4; j++)
        b[j] = *reinterpret_cast<const bf16x8*>(Bs + (wc + j * 16 + li) * 64 + kk);
#pragma unroll
      for (int i = 0; i < 4; i++)
#pragma unroll
        for (int j = 0; j < 4; j++)
          acc[i][j] = __builtin_amdgcn_mfma_f32_16x16x32_bf16(a[i], b[j], acc[i][j], 0, 0, 0);
    }
  }
  const int rb = m0 + wr + g * 4;
  const int cb = n0 + wc + li;
#pragma unroll
  for (int j = 0; j < 4; j++) {
    const int c = cb + j * 16;
    const float bv = bias[c];
    const int hq = c >> 6, d = c & 63;
    const float sc = d < 32 ? 0.03125f : (d < 48 ? 0.0625f : 0.125f);
#pragma unroll
    for (int i = 0; i < 4; i++) {
#pragma unroll
      for (int r = 0; r < 4; r++) {
        const int t = rb + i * 16 + r;
        const float val = acc[i][j][r] + bv;
        if (c < 1024) {
          qs[((size_t)(hq * 2048 + t) << 6) + d] = f2bf(val * sc);
        } else if (c < 2048) {
          kbuf[((size_t)((hq - 16) * 2048 + t) << 6) + d] = f2bf(val);
        } else {
          vT[(size_t)((hq - 32) * 64 + d) * 2048 + t] = f2bf(val);
        }
      }
    }
  }
}

// per-head chunk offset table: off[qt] = sum_{j<qt} ceil((j+1)/4); off[16]=40
DEVI int chunk_off(int qt) {
  const int off[17] = {0,1,2,3,4,6,8,10,12,15,18,21,24,28,32,36,40};
  return off[qt];
}

// ---------------- flash attention partials: one block = (h, qt, chunk of <=4 K-tiles) ----------------
// LDS tiles are 16B-chunk XOR-swizzled (T2): slot = chunk ^ (row & 7) for 128B rows,
// chunk ^ (row & 15) for 256B rows. K/V staged via pre-swizzled GLOBAL source (rule #21).
__global__ __launch_bounds__(256) void k_attn_part(
    const unsigned short* __restrict__ qs, const unsigned short* __restrict__ kbuf,
    const unsigned short* __restrict__ vT,
    float* __restrict__ o_part, float* __restrict__ ml) {
  __shared__ __align__(16) unsigned short Ks[128 * 64];   // [t2][d], swz &7
  __shared__ __align__(16) unsigned short Vs[64 * 128];   // [d][t2], swz &15
  __shared__ __align__(16) unsigned short Ps[128 * 128];  // [q'][t2], swz &15
  const int lane = threadIdx.x & 63, wid = threadIdx.x >> 6;
  const int g = lane >> 4, li = lane & 15;

  // decode work unit
  const int h = blockIdx.x / 40;
  const int rem = blockIdx.x % 40;
  int qt = 0;
#pragma unroll
  for (int i = 0; i < 16; i++)
    if (rem >= chunk_off(i + 1)) qt = i + 1;
  const int ci = rem - chunk_off(qt);
  const int kt0 = ci * 4;
  const int kt1 = min(qt, kt0 + 3);
  const int q0 = qt * 128;

  const f32x4 fzero = {0.f, 0.f, 0.f, 0.f};
  const bf16x8 bzero = {0, 0, 0, 0, 0, 0, 0, 0};

  // Q fragments: wave owns rows [wid*32, wid*32+32)
  bf16x8 qf[2][2];
#pragma unroll
  for (int mi = 0; mi < 2; mi++)
#pragma unroll
    for (int ks = 0; ks < 2; ks++) {
      const int t = q0 + wid * 32 + mi * 16 + li;
      const int d = ks * 32 + g * 8;
      qf[mi][ks] = *reinterpret_cast<const bf16x8*>(qs + ((size_t)(h * 2048 + t) << 6) + d);
    }

  f32x4 o[2][4] = {};
  float m_run[8], l_run[8];
#pragma unroll
  for (int i = 0; i < 8; i++) { m_run[i] = -1e30f; l_run[i] = 0.f; }

  const int q256 = qt >> 1;
  for (int kt = kt0; kt <= kt1; kt++) {
    __syncthreads();
    // stage K tile [128][64] and V tile [64][128]; source pre-swizzled so that
    // linear LDS dest holds chunk c of row r at slot c ^ (r & mask)
    for (int c = wid; c < 16; c += 4) {
      const int fb = c * 1024;
      const int flat = fb + lane * 16;
      {
        const int row = flat >> 7;
        const int cs = (((flat >> 4) & 7) ^ (row & 7)) << 4;
        g2l16((const char*)kbuf + (((size_t)(h * 2048 + kt * 128 + row)) << 7) + cs,
              (char*)Ks + fb);
      }
      {
        const int row = flat >> 8;
        const int cs = (((flat >> 4) & 15) ^ (row & 15)) << 4;
        g2l16((const char*)vT + ((size_t)(h * 64 + row) * 2048 + kt * 128) * 2 + cs,
              (char*)Vs + fb);
      }
    }
    __syncthreads();

    const int x = q256 ^ (kt >> 1);
    const int Keff = (x == 0) ? 64 : ((x >= 4) ? 32 : ((x >= 2) ? 48 : 56));

    // S = Q K^T over first Keff dims (scaling folded into q)
    f32x4 s[2][8];
#pragma unroll
    for (int mi = 0; mi < 2; mi++)
#pragma unroll
      for (int cf = 0; cf < 8; cf++) s[mi][cf] = fzero;

#pragma unroll
    for (int cf = 0; cf < 8; cf++) {
      const int krow = cf * 16 + li;
      const bf16x8 b0 = *reinterpret_cast<const bf16x8*>(
          Ks + krow * 64 + ((g ^ (krow & 7)) << 3));
      s[0][cf] = __builtin_amdgcn_mfma_f32_16x16x32_bf16(qf[0][0], b0, s[0][cf], 0, 0, 0);
      s[1][cf] = __builtin_amdgcn_mfma_f32_16x16x32_bf16(qf[1][0], b0, s[1][cf], 0, 0, 0);
    }
    if (Keff > 32) {
      const bool zf = (32 + g * 8) >= Keff;
#pragma unroll
      for (int cf = 0; cf < 8; cf++) {
        const int krow = cf * 16 + li;
        bf16x8 b1 = *reinterpret_cast<const bf16x8*>(
            Ks + krow * 64 + (((4 + g) ^ (krow & 7)) << 3));
        if (zf) b1 = bzero;
        s[0][cf] = __builtin_amdgcn_mfma_f32_16x16x32_bf16(qf[0][1], b1, s[0][cf], 0, 0, 0);
        s[1][cf] = __builtin_amdgcn_mfma_f32_16x16x32_bf16(qf[1][1], b1, s[1][cf], 0, 0, 0);
      }
    }

    // causal mask on the diagonal tile
    if (kt == qt) {
#pragma unroll
      for (int mi = 0; mi < 2; mi++)
#pragma unroll
        for (int cf = 0; cf < 8; cf++)
#pragma unroll
          for (int r = 0; r < 4; r++) {
            const int t1 = wid * 32 + mi * 16 + g * 4 + r;
            const int t2 = cf * 16 + li;
            if (t2 > t1) s[mi][cf][r] = -1e30f;
          }
    }

    // online softmax: row max + rescale
    float mnew[8], corr[8];
#pragma unroll
    for (int mi = 0; mi < 2; mi++)
#pragma unroll
      for (int r = 0; r < 4; r++) {
        float tm = s[mi][0][r];
#pragma unroll
        for (int cf = 1; cf < 8; cf++) tm = fmaxf(tm, s[mi][cf][r]);
        tm = fmaxf(tm, __shfl_xor(tm, 1));
        tm = fmaxf(tm, __shfl_xor(tm, 2));
        tm = fmaxf(tm, __shfl_xor(tm, 4));
        tm = fmaxf(tm, __shfl_xor(tm, 8));
        const int idx = mi * 4 + r;
        const float mn = fmaxf(m_run[idx], tm);
        mnew[idx] = mn;
        corr[idx] = __expf(m_run[idx] - mn);
        m_run[idx] = mn;
      }
    // P = exp(S - m), row sums, P -> LDS (A-fragment layout for PV), swizzled store
#pragma unroll
    for (int mi = 0; mi < 2; mi++)
#pragma unroll
      for (int r = 0; r < 4; r++) {
        const int idx = mi * 4 + r;
        float sum = 0.f;
        const int prow = wid * 32 + mi * 16 + g * 4 + r;
        const int rlow = prow & 15;
        const int rowoff = prow * 128;
#pragma unroll
        for (int cf = 0; cf < 8; cf++) {
          const float p = __expf(s[mi][cf][r] - mnew[idx]);
          sum += p;
          const int chunk = cf * 2 + (li >> 3);
          Ps[rowoff + ((chunk ^ rlow) << 3) + (li & 7)] = f2bf(p);
        }
        sum += __shfl_xor(sum, 1);
        sum += __shfl_xor(sum, 2);
        sum += __shfl_xor(sum, 4);
        sum += __shfl_xor(sum, 8);
        l_run[idx] = l_run[idx] * corr[idx] + sum;
      }
#pragma unroll
    for (int mi = 0; mi < 2; mi++)
#pragma unroll
      for (int nf = 0; nf < 4; nf++)
#pragma unroll
        for (int r = 0; r < 4; r++)
          o[mi][nf][r] *= corr[mi * 4 + r];

    __syncthreads();

    // O += P V  (swizzled reads)
#pragma unroll
    for (int ks2 = 0; ks2 < 4; ks2++) {
      bf16x8 pa[2], vb[4];
#pragma unroll
      for (int mi = 0; mi < 2; mi++) {
        const int prow = wid * 32 + mi * 16 + li;
        pa[mi] = *reinterpret_cast<const bf16x8*>(
            Ps + prow * 128 + (((ks2 * 4 + g) ^ (prow & 15)) << 3));
      }
#pragma unroll
      for (int nf = 0; nf < 4; nf++) {
        const int vrow = nf * 16 + li;
        vb[nf] = *reinterpret_cast<const bf16x8*>(
            Vs + vrow * 128 + (((ks2 * 4 + g) ^ (vrow & 15)) << 3));
      }
#pragma unroll
      for (int mi = 0; mi < 2; mi++)
#pragma unroll
        for (int nf = 0; nf < 4; nf++)
          o[mi][nf] = __builtin_amdgcn_mfma_f32_16x16x32_bf16(pa[mi], vb[nf], o[mi][nf], 0, 0, 0);
    }
  }

  // write unnormalized partial O (fp32) + m,l
  const size_t pbase = (size_t)blockIdx.x * 8192;
#pragma unroll
  for (int mi = 0; mi < 2; mi++) {
#pragma unroll
    for (int nf = 0; nf < 4; nf++)
#pragma unroll
      for (int r = 0; r < 4; r++) {
        const int row = wid * 32 + mi * 16 + g * 4 + r;
        o_part[pbase + (size_t)row * 64 + nf * 16 + li] = o[mi][nf][r];
      }
  }
  if (li == 0) {
#pragma unroll
    for (int mi = 0; mi < 2; mi++)
#pragma unroll
      for (int r = 0; r < 4; r++) {
        const int row = wid * 32 + mi * 16 + g * 4 + r;
        ml[(size_t)blockIdx.x * 256 + row] = m_run[mi * 4 + r];
        ml[(size_t)blockIdx.x * 256 + 128 + row] = l_run[mi * 4 + r];
      }
  }
}

// ---------------- combine partials -> yb bf16 [t][h*64+d] ----------------
__global__ __launch_bounds__(256) void k_combine(
    const float* __restrict__ o_part, const float* __restrict__ ml,
    unsigned short* __restrict__ yb) {
  const int h = blockIdx.x >> 4, qt = blockIdx.x & 15;
  const int nc = (qt >> 2) + 1;
  const int base = h * 40 + chunk_off(qt);
  const int row = threadIdx.x >> 1;
  const int c0 = (threadIdx.x & 1) * 32;

  float m_i[4], l_i[4];
  float M = -1e30f;
  for (int ci = 0; ci < nc; ci++) {
    m_i[ci] = ml[(size_t)(base + ci) * 256 + row];
    l_i[ci] = ml[(size_t)(base + ci) * 256 + 128 + row];
    M = fmaxf(M, m_i[ci]);
  }
  float L = 0.f, w[4];
  for (int ci = 0; ci < nc; ci++) {
    w[ci] = __expf(m_i[ci] - M);
    L += w[ci] * l_i[ci];
  }
  const float inv = 1.0f / L;

  float acc[32];
#pragma unroll
  for (int j = 0; j < 32; j++) acc[j] = 0.f;
  for (int ci = 0; ci < nc; ci++) {
    const float* src = o_part + (size_t)(base + ci) * 8192 + (size_t)row * 64 + c0;
    const float wc = w[ci];
#pragma unroll
    for (int j4 = 0; j4 < 8; j4++) {
      float4 v = reinterpret_cast<const float4*>(src)[j4];
      acc[j4 * 4 + 0] += wc * v.x;
      acc[j4 * 4 + 1] += wc * v.y;
      acc[j4 * 4 + 2] += wc * v.z;
      acc[j4 * 4 + 3] += wc * v.w;
    }
  }
  const int t = qt * 128 + row;
  unsigned short* dst = yb + (size_t)t * 1024 + h * 64 + c0;
#pragma unroll
  for (int j8 = 0; j8 < 4; j8++) {
    ushort4 pk;
    pk.x = f2bf(acc[j8 * 8 + 0] * inv);
    pk.y = f2bf(acc[j8 * 8 + 1] * inv);
    pk.z = f2bf(acc[j8 * 8 + 2] * inv);
    pk.w = f2bf(acc[j8 * 8 + 3] * inv);
    ushort4 pk2;
    pk2.x = f2bf(acc[j8 * 8 + 4] * inv);
    pk2.y = f2bf(acc[j8 * 8 + 5] * inv);
    pk2.z = f2bf(acc[j8 * 8 + 6] * inv);
    pk2.w = f2bf(acc[j8 * 8 + 7] * inv);
    reinterpret_cast<ushort4*>(dst)[j8 * 2 + 0] = pk;
    reinterpret_cast<ushort4*>(dst)[j8 * 2 + 1] = pk2;
  }
}

// ---------------- proj GEMM: [2048,1024] x [1024,1024]^T -> fp32 out + bias ----------------
__global__ __launch_bounds__(256) void k_gemm_proj(
    const unsigned short* __restrict__ A, const unsigned short* __restrict__ Bt,
    const float* __restrict__ bias, float* __restrict__ out) {
  constexpr int K = 1024;
  __shared__ __align__(16) unsigned short As[128 * 64];
  __shared__ __align__(16) unsigned short Bs[128 * 64];
  const int lane = threadIdx.x & 63, wid = threadIdx.x >> 6;
  const int m0 = blockIdx.y * 128, n0 = blockIdx.x * 128;
  const int wr = (wid >> 1) * 64, wc = (wid & 1) * 64;
  const int g = lane >> 4, li = lane & 15;
  f32x4 acc[4][4] = {};
  for (int k0 = 0; k0 < K; k0 += 64) {
    __syncthreads();
    for (int c = wid; c < 16; c += 4) {
      const int fb = c * 1024;
      const int flat = fb + lane * 16;
      const int row = flat >> 7, colb = flat & 127;
      g2l16((const char*)A  + ((size_t)(m0 + row) * K + k0) * 2 + colb, (char*)As + fb);
      g2l16((const char*)Bt + ((size_t)(n0 + row) * K + k0) * 2 + colb, (char*)Bs + fb);
    }
    __syncthreads();
#pragma unroll
    for (int ks = 0; ks < 2; ks++) {
      const int kk = ks * 32 + g * 8;
      bf16x8 a[4], b[4];
#pragma unroll
      for (int i = 0; i < 4; i++)
        a[i] = *reinterpret_cast<const bf16x8*>(As + (wr + i * 16 + li) * 64 + kk);
#pragma unroll
      for (int j = 0; j < 4; j++)
        b[j] = *reinterpret_cast<const bf16x8*>(Bs + (wc + j * 16 + li) * 64 + kk);
#pragma unroll
      for (int i = 0; i < 4; i++)
#pragma unroll
        for (int j = 0; j < 4; j++)
          acc[i][j] = __builtin_amdgcn_mfma_f32_16x16x32_bf16(a[i], b[j], acc[i][j], 0, 0, 0);
    }
  }
  const int rb = m0 + wr + g * 4;
  const int cb = n0 + wc + li;
#pragma unroll
  for (int j = 0; j < 4; j++) {
    const int c = cb + j * 16;
    const float bv = bias[c];
#pragma unroll
    for (int i = 0; i < 4; i++) {
#pragma unroll
      for (int r = 0; r < 4; r++) {
        const int t = rb + i * 16 + r;
        out[(size_t)t * 1024 + c] = acc[i][j][r] + bv;
      }
    }
  }
}

extern "C" void kernel_launch(void* const* d_in, const int* in_sizes, int n_in,
                              void* d_out, int out_size, void* d_ws, size_t ws_size,
                              hipStream_t stream) {
  const float* x      = (const float*)d_in[0];
  const float* W_attn = (const float*)d_in[1];
  const float* b_attn = (const float*)d_in[2];
  const float* W_proj = (const float*)d_in[3];
  const float* b_proj = (const float*)d_in[4];
  float* out = (float*)d_out;
  char* ws = (char*)d_ws;
  const size_t MB = 1024 * 1024;
  unsigned short* xb  = (unsigned short*)(ws + 0 * MB);   // [2048][1024] bf16
  unsigned short* WaT = (unsigned short*)(ws + 4 * MB);   // [3072][1024] bf16
  unsigned short* WpT = (unsigned short*)(ws + 10 * MB);  // [1024][1024] bf16
  unsigned short* qs  = (unsigned short*)(ws + 12 * MB);  // [16][2048][64] bf16, pre-scaled
  unsigned short* kb  = (unsigned short*)(ws + 16 * MB);  // [16][2048][64] bf16
  unsigned short* vT  = (unsigned short*)(ws + 20 * MB);  // [16][64][2048] bf16
  unsigned short* yb  = (unsigned short*)(ws + 24 * MB);  // [2048][1024] bf16
  float* o_part = (float*)(ws + 28 * MB);                 // [640][128][64] fp32 (20 MB)
  float* ml     = (float*)(ws + 48 * MB + 256 * 1024);    // [640][2][128] fp32

  k_convx<<<dim3(2048), dim3(256), 0, stream>>>(x, xb, 524288);
  k_tconv<<<dim3(96, 32), dim3(32, 8), 0, stream>>>(W_attn, WaT, 1024, 3072);
  k_tconv<<<dim3(32, 32), dim3(32, 8), 0, stream>>>(W_proj, WpT, 1024, 1024);
  k_gemm_qkv<<<dim3(24, 16), dim3(256), 0, stream>>>(xb, WaT, b_attn, qs, kb, vT);
  k_attn_part<<<dim3(640), dim3(256), 0, stream>>>(qs, kb, vT, o_part, ml);
  k_combine<<<dim3(256), dim3(256), 0, stream>>>(o_part, ml, yb);
  k_gemm_proj<<<dim3(8, 16), dim3(256), 0, stream>>>(yb, WpT, b_proj, out);
}

// Round 4
// 110.296 us; speedup vs baseline: 1.2293x; 1.2293x over previous
//
#include <hip/hip_runtime.h>

using bf16x8 = __attribute__((ext_vector_type(8))) short;
using f32x4  = __attribute__((ext_vector_type(4))) float;

#define DEVI __device__ __forceinline__

// round-to-nearest-even fp32 -> bf16 (bit pattern)
DEVI unsigned short f2bf(float f) {
  union { float ff; unsigned u; } v; v.ff = f;
  unsigned r = v.u + 0x7FFFu + ((v.u >> 16) & 1u);
  return (unsigned short)(r >> 16);
}

// pack two f32 -> one dword of 2 bf16 (RNE), low = lo, high = hi
DEVI int cvtpk(float lo, float hi) {
  int r;
  asm("v_cvt_pk_bf16_f32 %0, %1, %2" : "=v"(r) : "v"(lo), "v"(hi));
  return r;
}

// async global->LDS, 16B per lane; l must be wave-uniform base (HW adds lane*16)
DEVI void g2l16(const void* g, void* l) {
  __builtin_amdgcn_global_load_lds(
      (const __attribute__((address_space(1))) unsigned int*)g,
      (__attribute__((address_space(3))) unsigned int*)l, 16, 0, 0);
}

// ---------------- x fp32 -> bf16 ----------------
__global__ void k_convx(const float* __restrict__ in, unsigned short* __restrict__ out, int n4) {
  int i = blockIdx.x * 256 + threadIdx.x;
  if (i >= n4) return;
  float4 v = reinterpret_cast<const float4*>(in)[i];
  ushort4 o;
  o.x = f2bf(v.x); o.y = f2bf(v.y); o.z = f2bf(v.z); o.w = f2bf(v.w);
  reinterpret_cast<ushort4*>(out)[i] = o;
}

// ---------------- transpose+convert: out[c][r] = bf16(in[r][c]) ----------------
__global__ void k_tconv(const float* __restrict__ in, unsigned short* __restrict__ out, int R, int C) {
  __shared__ float tile[32][33];
  int c0 = blockIdx.x * 32, r0 = blockIdx.y * 32;
  int x = threadIdx.x, y = threadIdx.y;  // block (32,8)
  for (int i = y; i < 32; i += 8) tile[i][x] = in[(size_t)(r0 + i) * C + c0 + x];
  __syncthreads();
  for (int i = y; i < 32; i += 8) out[(size_t)(c0 + i) * R + r0 + x] = f2bf(tile[x][i]);
}

// ---------------- QKV GEMM: [2048,1024] x [3072,1024]^T, epilogue scatters q/k/vT ----------------
__global__ __launch_bounds__(256) void k_gemm_qkv(
    const unsigned short* __restrict__ A, const unsigned short* __restrict__ Bt,
    const float* __restrict__ bias,
    unsigned short* __restrict__ qs, unsigned short* __restrict__ kbuf,
    unsigned short* __restrict__ vT) {
  constexpr int K = 1024;
  __shared__ __align__(16) unsigned short As[128 * 64];
  __shared__ __align__(16) unsigned short Bs[128 * 64];
  const int lane = threadIdx.x & 63, wid = threadIdx.x >> 6;
  const int m0 = blockIdx.y * 128, n0 = blockIdx.x * 128;
  const int wr = (wid >> 1) * 64, wc = (wid & 1) * 64;
  const int g = lane >> 4, li = lane & 15;
  f32x4 acc[4][4] = {};
  for (int k0 = 0; k0 < K; k0 += 64) {
    __syncthreads();
    for (int c = wid; c < 16; c += 4) {
      const int fb = c * 1024;
      const int flat = fb + lane * 16;
      const int row = flat >> 7, colb = flat & 127;
      g2l16((const char*)A  + ((size_t)(m0 + row) * K + k0) * 2 + colb, (char*)As + fb);
      g2l16((const char*)Bt + ((size_t)(n0 + row) * K + k0) * 2 + colb, (char*)Bs + fb);
    }
    __syncthreads();
#pragma unroll
    for (int ks = 0; ks < 2; ks++) {
      const int kk = ks * 32 + g * 8;
      bf16x8 a[4], b[4];
#pragma unroll
      for (int i = 0; i < 4; i++)
        a[i] = *reinterpret_cast<const bf16x8*>(As + (wr + i * 16 + li) * 64 + kk);
#pragma unroll
      for (int j = 0; j < 4; j++)
        b[j] = *reinterpret_cast<const bf16x8*>(Bs + (wc + j * 16 + li) * 64 + kk);
#pragma unroll
      for (int i = 0; i < 4; i++)
#pragma unroll
        for (int j = 0; j < 4; j++)
          acc[i][j] = __builtin_amdgcn_mfma_f32_16x16x32_bf16(a[i], b[j], acc[i][j], 0, 0, 0);
    }
  }
  const int rb = m0 + wr + g * 4;
  const int cb = n0 + wc + li;
#pragma unroll
  for (int j = 0; j < 4; j++) {
    const int c = cb + j * 16;
    const float bv = bias[c];
    const int hq = c >> 6, d = c & 63;
    const float sc = d < 32 ? 0.03125f : (d < 48 ? 0.0625f : 0.125f);
#pragma unroll
    for (int i = 0; i < 4; i++) {
#pragma unroll
      for (int r = 0; r < 4; r++) {
        const int t = rb + i * 16 + r;
        const float val = acc[i][j][r] + bv;
        if (c < 1024) {
          qs[((size_t)(hq * 2048 + t) << 6) + d] = f2bf(val * sc);
        } else if (c < 2048) {
          kbuf[((size_t)((hq - 16) * 2048 + t) << 6) + d] = f2bf(val);
        } else {
          vT[(size_t)((hq - 32) * 64 + d) * 2048 + t] = f2bf(val);
        }
      }
    }
  }
}

// per-head chunk offset table: off[qt] = sum_{j<qt} ceil((j+1)/4); off[16]=40
DEVI int chunk_off(int qt) {
  const int off[17] = {0,1,2,3,4,6,8,10,12,15,18,21,24,28,32,36,40};
  return off[qt];
}

// ---------------- flash attention partials: one block = (h, qt, chunk of <=4 K-tiles) ----------------
// Swapped QK^T (S^T = mfma(K, Q)) keeps P lane-local: lane (g,li) holds P[q=li][t2=cf*16+4g+r].
// PV uses a custom k-relabeling (k-slot (g,j) -> t2 = 32*ks2 + (j<4 ? 4g+j : 16+4g+j-4)) applied
// to BOTH operands, so packed P dwords feed the A-operand from own registers (no LDS, no shuffle);
// V pays 2x ds_read_b64 per fragment. K/V LDS tiles 16B-chunk XOR-swizzled via pre-swizzled
// global source (rule #21).
__global__ __launch_bounds__(256) void k_attn_part(
    const unsigned short* __restrict__ qs, const unsigned short* __restrict__ kbuf,
    const unsigned short* __restrict__ vT,
    float* __restrict__ o_part, float* __restrict__ ml) {
  __shared__ __align__(16) unsigned short Ks[128 * 64];   // [t2][d], swz &7
  __shared__ __align__(16) unsigned short Vs[64 * 128];   // [d][t2], swz &15
  const int lane = threadIdx.x & 63, wid = threadIdx.x >> 6;
  const int g = lane >> 4, li = lane & 15;

  // decode work unit
  const int h = blockIdx.x / 40;
  const int rem = blockIdx.x % 40;
  int qt = 0;
#pragma unroll
  for (int i = 0; i < 16; i++)
    if (rem >= chunk_off(i + 1)) qt = i + 1;
  const int ci = rem - chunk_off(qt);
  const int kt0 = ci * 4;
  const int kt1 = min(qt, kt0 + 3);
  const int q0 = qt * 128;

  const bf16x8 bzero = {0, 0, 0, 0, 0, 0, 0, 0};

  // Q fragments (B-operand): lane holds Q[q=li][d=g*8..+7]; wave owns rows [wid*32, wid*32+32)
  bf16x8 qf[2][2];
#pragma unroll
  for (int mi = 0; mi < 2; mi++)
#pragma unroll
    for (int ks = 0; ks < 2; ks++) {
      const int t = q0 + wid * 32 + mi * 16 + li;
      const int d = ks * 32 + g * 8;
      qf[mi][ks] = *reinterpret_cast<const bf16x8*>(qs + ((size_t)(h * 2048 + t) << 6) + d);
    }

  f32x4 o[2][4] = {};
  float m_run[2] = {-1e30f, -1e30f}, l_run[2] = {0.f, 0.f};

  const int q256 = qt >> 1;
  for (int kt = kt0; kt <= kt1; kt++) {
    __syncthreads();
    // stage K tile [128][64] and V tile [64][128]; source pre-swizzled so that
    // linear LDS dest holds chunk c of row r at slot c ^ (r & mask)
    for (int c = wid; c < 16; c += 4) {
      const int fb = c * 1024;
      const int flat = fb + lane * 16;
      {
        const int row = flat >> 7;
        const int cs = (((flat >> 4) & 7) ^ (row & 7)) << 4;
        g2l16((const char*)kbuf + (((size_t)(h * 2048 + kt * 128 + row)) << 7) + cs,
              (char*)Ks + fb);
      }
      {
        const int row = flat >> 8;
        const int cs = (((flat >> 4) & 15) ^ (row & 15)) << 4;
        g2l16((const char*)vT + ((size_t)(h * 64 + row) * 2048 + kt * 128) * 2 + cs,
              (char*)Vs + fb);
      }
    }
    __syncthreads();

    const int x = q256 ^ (kt >> 1);
    const int Keff = (x == 0) ? 64 : ((x >= 4) ? 32 : ((x >= 2) ? 48 : 56));

    // S^T = mfma(K, Q): st[cf][mi], lane (g,li): q = li, t2 = cf*16 + g*4 + r
    f32x4 st[8][2] = {};
#pragma unroll
    for (int cf = 0; cf < 8; cf++) {
      const int krow = cf * 16 + li;
      const bf16x8 a0 = *reinterpret_cast<const bf16x8*>(
          Ks + krow * 64 + ((g ^ (krow & 7)) << 3));
      st[cf][0] = __builtin_amdgcn_mfma_f32_16x16x32_bf16(a0, qf[0][0], st[cf][0], 0, 0, 0);
      st[cf][1] = __builtin_amdgcn_mfma_f32_16x16x32_bf16(a0, qf[1][0], st[cf][1], 0, 0, 0);
    }
    if (Keff > 32) {
      const bool zf = (32 + g * 8) >= Keff;
#pragma unroll
      for (int cf = 0; cf < 8; cf++) {
        const int krow = cf * 16 + li;
        bf16x8 a1 = *reinterpret_cast<const bf16x8*>(
            Ks + krow * 64 + (((4 + g) ^ (krow & 7)) << 3));
        if (zf) a1 = bzero;
        st[cf][0] = __builtin_amdgcn_mfma_f32_16x16x32_bf16(a1, qf[0][1], st[cf][0], 0, 0, 0);
        st[cf][1] = __builtin_amdgcn_mfma_f32_16x16x32_bf16(a1, qf[1][1], st[cf][1], 0, 0, 0);
      }
    }

    // causal mask on the diagonal tile: t2 > q
    if (kt == qt) {
#pragma unroll
      for (int cf = 0; cf < 8; cf++)
#pragma unroll
        for (int mi = 0; mi < 2; mi++)
#pragma unroll
          for (int r = 0; r < 4; r++) {
            const int t2 = cf * 16 + g * 4 + r;
            const int qq = wid * 32 + mi * 16 + li;
            if (t2 > qq) st[cf][mi][r] = -1e30f;
          }
    }

    // online softmax (row = q = li, in-lane over 32 t2 + cross-group xor16/32) + pack to bf16
    int pk[2][8][2];
    float corrb[2][4];
#pragma unroll
    for (int mi = 0; mi < 2; mi++) {
      float tm = st[0][mi][0];
#pragma unroll
      for (int cf = 0; cf < 8; cf++)
#pragma unroll
        for (int r = 0; r < 4; r++)
          if (cf | r) tm = fmaxf(tm, st[cf][mi][r]);
      tm = fmaxf(tm, __shfl_xor(tm, 16));
      tm = fmaxf(tm, __shfl_xor(tm, 32));
      const float mn = fmaxf(m_run[mi], tm);
      const float corr = __expf(m_run[mi] - mn);
      m_run[mi] = mn;
      float sum = 0.f;
#pragma unroll
      for (int cf = 0; cf < 8; cf++) {
        const float p0 = __expf(st[cf][mi][0] - mn);
        const float p1 = __expf(st[cf][mi][1] - mn);
        const float p2 = __expf(st[cf][mi][2] - mn);
        const float p3 = __expf(st[cf][mi][3] - mn);
        sum += (p0 + p1) + (p2 + p3);
        pk[mi][cf][0] = cvtpk(p0, p1);
        pk[mi][cf][1] = cvtpk(p2, p3);
      }
      sum += __shfl_xor(sum, 16);
      sum += __shfl_xor(sum, 32);
      l_run[mi] = l_run[mi] * corr + sum;
      // broadcast corr from softmax layout (q=li) to O layout (q=g*4+r)
      corrb[mi][0] = __shfl(corr, 4 * g + 0);
      corrb[mi][1] = __shfl(corr, 4 * g + 1);
      corrb[mi][2] = __shfl(corr, 4 * g + 2);
      corrb[mi][3] = __shfl(corr, 4 * g + 3);
    }
#pragma unroll
    for (int mi = 0; mi < 2; mi++)
#pragma unroll
      for (int nf = 0; nf < 4; nf++)
#pragma unroll
        for (int r = 0; r < 4; r++)
          o[mi][nf][r] *= corrb[mi][r];

    // O += P V with custom k-labeling; P from own registers, V via 2x b64 swizzled reads
#pragma unroll
    for (int ks2 = 0; ks2 < 4; ks2++) {
      bf16x8 pa[2];
#pragma unroll
      for (int mi = 0; mi < 2; mi++) {
        union { int i[4]; bf16x8 v; } u;
        u.i[0] = pk[mi][2 * ks2][0];
        u.i[1] = pk[mi][2 * ks2][1];
        u.i[2] = pk[mi][2 * ks2 + 1][0];
        u.i[3] = pk[mi][2 * ks2 + 1][1];
        pa[mi] = u.v;
      }
      bf16x8 vb[4];
#pragma unroll
      for (int nf = 0; nf < 4; nf++) {
        const int vrow = nf * 16 + li;
        const int rm = vrow & 15;
        const int ch0 = 4 * ks2 + (g >> 1);
        const int b8 = (g & 1) * 8;
        union { struct { int2 lo, hi; } p; bf16x8 v; } u;
        u.p.lo = *reinterpret_cast<const int2*>(
            (const char*)Vs + vrow * 256 + (((ch0 + 0) ^ rm) << 4) + b8);
        u.p.hi = *reinterpret_cast<const int2*>(
            (const char*)Vs + vrow * 256 + (((ch0 + 2) ^ rm) << 4) + b8);
        vb[nf] = u.v;
      }
#pragma unroll
      for (int mi = 0; mi < 2; mi++)
#pragma unroll
        for (int nf = 0; nf < 4; nf++)
          o[mi][nf] = __builtin_amdgcn_mfma_f32_16x16x32_bf16(pa[mi], vb[nf], o[mi][nf], 0, 0, 0);
    }
  }

  // write unnormalized partial O (fp32) + m,l
  const size_t pbase = (size_t)blockIdx.x * 8192;
#pragma unroll
  for (int mi = 0; mi < 2; mi++) {
#pragma unroll
    for (int nf = 0; nf < 4; nf++)
#pragma unroll
      for (int r = 0; r < 4; r++) {
        const int row = wid * 32 + mi * 16 + g * 4 + r;
        o_part[pbase + (size_t)row * 64 + nf * 16 + li] = o[mi][nf][r];
      }
  }
  if (g == 0) {
#pragma unroll
    for (int mi = 0; mi < 2; mi++) {
      const int row = wid * 32 + mi * 16 + li;
      ml[(size_t)blockIdx.x * 256 + row] = m_run[mi];
      ml[(size_t)blockIdx.x * 256 + 128 + row] = l_run[mi];
    }
  }
}

// ---------------- combine partials -> yb bf16 [t][h*64+d] ----------------
__global__ __launch_bounds__(256) void k_combine(
    const float* __restrict__ o_part, const float* __restrict__ ml,
    unsigned short* __restrict__ yb) {
  const int h = blockIdx.x >> 4, qt = blockIdx.x & 15;
  const int nc = (qt >> 2) + 1;
  const int base = h * 40 + chunk_off(qt);
  const int row = threadIdx.x >> 1;
  const int c0 = (threadIdx.x & 1) * 32;

  float m_i[4], l_i[4];
  float M = -1e30f;
  for (int ci = 0; ci < nc; ci++) {
    m_i[ci] = ml[(size_t)(base + ci) * 256 + row];
    l_i[ci] = ml[(size_t)(base + ci) * 256 + 128 + row];
    M = fmaxf(M, m_i[ci]);
  }
  float L = 0.f, w[4];
  for (int ci = 0; ci < nc; ci++) {
    w[ci] = __expf(m_i[ci] - M);
    L += w[ci] * l_i[ci];
  }
  const float inv = 1.0f / L;

  float acc[32];
#pragma unroll
  for (int j = 0; j < 32; j++) acc[j] = 0.f;
  for (int ci = 0; ci < nc; ci++) {
    const float* src = o_part + (size_t)(base + ci) * 8192 + (size_t)row * 64 + c0;
    const float wc = w[ci];
#pragma unroll
    for (int j4 = 0; j4 < 8; j4++) {
      float4 v = reinterpret_cast<const float4*>(src)[j4];
      acc[j4 * 4 + 0] += wc * v.x;
      acc[j4 * 4 + 1] += wc * v.y;
      acc[j4 * 4 + 2] += wc * v.z;
      acc[j4 * 4 + 3] += wc * v.w;
    }
  }
  const int t = qt * 128 + row;
  unsigned short* dst = yb + (size_t)t * 1024 + h * 64 + c0;
#pragma unroll
  for (int j8 = 0; j8 < 4; j8++) {
    ushort4 pk;
    pk.x = f2bf(acc[j8 * 8 + 0] * inv);
    pk.y = f2bf(acc[j8 * 8 + 1] * inv);
    pk.z = f2bf(acc[j8 * 8 + 2] * inv);
    pk.w = f2bf(acc[j8 * 8 + 3] * inv);
    ushort4 pk2;
    pk2.x = f2bf(acc[j8 * 8 + 4] * inv);
    pk2.y = f2bf(acc[j8 * 8 + 5] * inv);
    pk2.z = f2bf(acc[j8 * 8 + 6] * inv);
    pk2.w = f2bf(acc[j8 * 8 + 7] * inv);
    reinterpret_cast<ushort4*>(dst)[j8 * 2 + 0] = pk;
    reinterpret_cast<ushort4*>(dst)[j8 * 2 + 1] = pk2;
  }
}

// ---------------- proj GEMM: [2048,1024] x [1024,1024]^T -> fp32 out + bias ----------------
__global__ __launch_bounds__(256) void k_gemm_proj(
    const unsigned short* __restrict__ A, const unsigned short* __restrict__ Bt,
    const float* __restrict__ bias, float* __restrict__ out) {
  constexpr int K = 1024;
  __shared__ __align__(16) unsigned short As[128 * 64];
  __shared__ __align__(16) unsigned short Bs[128 * 64];
  const int lane = threadIdx.x & 63, wid = threadIdx.x >> 6;
  const int m0 = blockIdx.y * 128, n0 = blockIdx.x * 128;
  const int wr = (wid >> 1) * 64, wc = (wid & 1) * 64;
  const int g = lane >> 4, li = lane & 15;
  f32x4 acc[4][4] = {};
  for (int k0 = 0; k0 < K; k0 += 64) {
    __syncthreads();
    for (int c = wid; c < 16; c += 4) {
      const int fb = c * 1024;
      const int flat = fb + lane * 16;
      const int row = flat >> 7, colb = flat & 127;
      g2l16((const char*)A  + ((size_t)(m0 + row) * K + k0) * 2 + colb, (char*)As + fb);
      g2l16((const char*)Bt + ((size_t)(n0 + row) * K + k0) * 2 + colb, (char*)Bs + fb);
    }
    __syncthreads();
#pragma unroll
    for (int ks = 0; ks < 2; ks++) {
      const int kk = ks * 32 + g * 8;
      bf16x8 a[4], b[4];
#pragma unroll
      for (int i = 0; i < 4; i++)
        a[i] = *reinterpret_cast<const bf16x8*>(As + (wr + i * 16 + li) * 64 + kk);
#pragma unroll
      for (int j = 0; j < 4; j++)
        b[j] = *reinterpret_cast<const bf16x8*>(Bs + (wc + j * 16 + li) * 64 + kk);
#pragma unroll
      for (int i = 0; i < 4; i++)
#pragma unroll
        for (int j = 0; j < 4; j++)
          acc[i][j] = __builtin_amdgcn_mfma_f32_16x16x32_bf16(a[i], b[j], acc[i][j], 0, 0, 0);
    }
  }
  const int rb = m0 + wr + g * 4;
  const int cb = n0 + wc + li;
#pragma unroll
  for (int j = 0; j < 4; j++) {
    const int c = cb + j * 16;
    const float bv = bias[c];
#pragma unroll
    for (int i = 0; i < 4; i++) {
#pragma unroll
      for (int r = 0; r < 4; r++) {
        const int t = rb + i * 16 + r;
        out[(size_t)t * 1024 + c] = acc[i][j][r] + bv;
      }
    }
  }
}

extern "C" void kernel_launch(void* const* d_in, const int* in_sizes, int n_in,
                              void* d_out, int out_size, void* d_ws, size_t ws_size,
                              hipStream_t stream) {
  const float* x      = (const float*)d_in[0];
  const float* W_attn = (const float*)d_in[1];
  const float* b_attn = (const float*)d_in[2];
  const float* W_proj = (const float*)d_in[3];
  const float* b_proj = (const float*)d_in[4];
  float* out = (float*)d_out;
  char* ws = (char*)d_ws;
  const size_t MB = 1024 * 1024;
  unsigned short* xb  = (unsigned short*)(ws + 0 * MB);   // [2048][1024] bf16
  unsigned short* WaT = (unsigned short*)(ws + 4 * MB);   // [3072][1024] bf16
  unsigned short* WpT = (unsigned short*)(ws + 10 * MB);  // [1024][1024] bf16
  unsigned short* qs  = (unsigned short*)(ws + 12 * MB);  // [16][2048][64] bf16, pre-scaled
  unsigned short* kb  = (unsigned short*)(ws + 16 * MB);  // [16][2048][64] bf16
  unsigned short* vT  = (unsigned short*)(ws + 20 * MB);  // [16][64][2048] bf16
  unsigned short* yb  = (unsigned short*)(ws + 24 * MB);  // [2048][1024] bf16
  float* o_part = (float*)(ws + 28 * MB);                 // [640][128][64] fp32 (20 MB)
  float* ml     = (float*)(ws + 48 * MB + 256 * 1024);    // [640][2][128] fp32

  k_convx<<<dim3(2048), dim3(256), 0, stream>>>(x, xb, 524288);
  k_tconv<<<dim3(96, 32), dim3(32, 8), 0, stream>>>(W_attn, WaT, 1024, 3072);
  k_tconv<<<dim3(32, 32), dim3(32, 8), 0, stream>>>(W_proj, WpT, 1024, 1024);
  k_gemm_qkv<<<dim3(24, 16), dim3(256), 0, stream>>>(xb, WaT, b_attn, qs, kb, vT);
  k_attn_part<<<dim3(640), dim3(256), 0, stream>>>(qs, kb, vT, o_part, ml);
  k_combine<<<dim3(256), dim3(256), 0, stream>>>(o_part, ml, yb);
  k_gemm_proj<<<dim3(8, 16), dim3(256), 0, stream>>>(yb, WpT, b_proj, out);
}

// Round 5
// 103.741 us; speedup vs baseline: 1.3069x; 1.0632x over previous
//
#include <hip/hip_runtime.h>

using bf16x8 = __attribute__((ext_vector_type(8))) short;
using f32x4  = __attribute__((ext_vector_type(4))) float;

#define DEVI __device__ __forceinline__

// round-to-nearest-even fp32 -> bf16 (bit pattern)
DEVI unsigned short f2bf(float f) {
  union { float ff; unsigned u; } v; v.ff = f;
  unsigned r = v.u + 0x7FFFu + ((v.u >> 16) & 1u);
  return (unsigned short)(r >> 16);
}

// pack two f32 -> one dword of 2 bf16 (RNE), low = lo, high = hi
DEVI int cvtpk(float lo, float hi) {
  int r;
  asm("v_cvt_pk_bf16_f32 %0, %1, %2" : "=v"(r) : "v"(lo), "v"(hi));
  return r;
}

// async global->LDS, 16B per lane; l must be wave-uniform base (HW adds lane*16)
DEVI void g2l16(const void* g, void* l) {
  __builtin_amdgcn_global_load_lds(
      (const __attribute__((address_space(1))) unsigned int*)g,
      (__attribute__((address_space(3))) unsigned int*)l, 16, 0, 0);
}

// ---------------- x fp32 -> bf16 ----------------
__global__ void k_convx(const float* __restrict__ in, unsigned short* __restrict__ out, int n4) {
  int i = blockIdx.x * 256 + threadIdx.x;
  if (i >= n4) return;
  float4 v = reinterpret_cast<const float4*>(in)[i];
  ushort4 o;
  o.x = f2bf(v.x); o.y = f2bf(v.y); o.z = f2bf(v.z); o.w = f2bf(v.w);
  reinterpret_cast<ushort4*>(out)[i] = o;
}

// ---------------- transpose+convert: out[c][r] = bf16(in[r][c]) ----------------
__global__ void k_tconv(const float* __restrict__ in, unsigned short* __restrict__ out, int R, int C) {
  __shared__ float tile[32][33];
  int c0 = blockIdx.x * 32, r0 = blockIdx.y * 32;
  int x = threadIdx.x, y = threadIdx.y;  // block (32,8)
  for (int i = y; i < 32; i += 8) tile[i][x] = in[(size_t)(r0 + i) * C + c0 + x];
  __syncthreads();
  for (int i = y; i < 32; i += 8) out[(size_t)(c0 + i) * R + r0 + x] = f2bf(tile[x][i]);
}

// ---------------- QKV GEMM: 128x64 tile, 2-phase dbuf pipeline ----------------
// grid (48, 16): x = n-tile (64 cols), y = m-tile (128 rows). 768 blocks.
__global__ __launch_bounds__(256) void k_gemm_qkv(
    const unsigned short* __restrict__ A, const unsigned short* __restrict__ Bt,
    const float* __restrict__ bias,
    unsigned short* __restrict__ qs, unsigned short* __restrict__ kbuf,
    unsigned short* __restrict__ vT) {
  constexpr int K = 1024;
  __shared__ __align__(16) unsigned short As[2][128 * 64];
  __shared__ __align__(16) unsigned short Bs[2][64 * 64];
  const int lane = threadIdx.x & 63, wid = threadIdx.x >> 6;
  const int m0 = blockIdx.y * 128, n0 = blockIdx.x * 64;
  const int wr = (wid >> 1) * 64, wc = (wid & 1) * 32;
  const int g = lane >> 4, li = lane & 15;
  f32x4 acc[4][2] = {};

#define STAGE_QKV(buf, k0)                                                              \
  {                                                                                     \
    _Pragma("unroll")                                                                   \
    for (int c = wid * 4; c < wid * 4 + 4; c++) {                                       \
      const int flat = c * 1024 + lane * 16;                                            \
      const int row = flat >> 7, colb = flat & 127;                                     \
      g2l16((const char*)A + ((size_t)(m0 + row) * K + (k0)) * 2 + colb,                \
            (char*)As[buf] + c * 1024);                                                 \
    }                                                                                   \
    _Pragma("unroll")                                                                   \
    for (int c = wid * 2; c < wid * 2 + 2; c++) {                                       \
      const int flat = c * 1024 + lane * 16;                                            \
      const int row = flat >> 7, colb = flat & 127;                                     \
      g2l16((const char*)Bt + ((size_t)(n0 + row) * K + (k0)) * 2 + colb,               \
            (char*)Bs[buf] + c * 1024);                                                 \
    }                                                                                   \
  }

  STAGE_QKV(0, 0);
  __syncthreads();
  int buf = 0;
  for (int t = 0; t < 16; t++) {
    if (t < 15) STAGE_QKV(buf ^ 1, (t + 1) * 64);
#pragma unroll
    for (int ks = 0; ks < 2; ks++) {
      const int kk = ks * 32 + g * 8;
      bf16x8 a[4], b[2];
#pragma unroll
      for (int i = 0; i < 4; i++)
        a[i] = *reinterpret_cast<const bf16x8*>(As[buf] + (wr + i * 16 + li) * 64 + kk);
#pragma unroll
      for (int j = 0; j < 2; j++)
        b[j] = *reinterpret_cast<const bf16x8*>(Bs[buf] + (wc + j * 16 + li) * 64 + kk);
#pragma unroll
      for (int i = 0; i < 4; i++)
#pragma unroll
        for (int j = 0; j < 2; j++)
          acc[i][j] = __builtin_amdgcn_mfma_f32_16x16x32_bf16(a[i], b[j], acc[i][j], 0, 0, 0);
    }
    __syncthreads();
    buf ^= 1;
  }

  const int rb = m0 + wr + g * 4;
  const int cb = n0 + wc + li;
#pragma unroll
  for (int j = 0; j < 2; j++) {
    const int c = cb + j * 16;
    const float bv = bias[c];
    const int hq = c >> 6, d = c & 63;
    const float sc = d < 32 ? 0.03125f : (d < 48 ? 0.0625f : 0.125f);
#pragma unroll
    for (int i = 0; i < 4; i++) {
#pragma unroll
      for (int r = 0; r < 4; r++) {
        const int t = rb + i * 16 + r;
        const float val = acc[i][j][r] + bv;
        if (c < 1024) {
          qs[((size_t)(hq * 2048 + t) << 6) + d] = f2bf(val * sc);
        } else if (c < 2048) {
          kbuf[((size_t)((hq - 16) * 2048 + t) << 6) + d] = f2bf(val);
        } else {
          vT[(size_t)((hq - 32) * 64 + d) * 2048 + t] = f2bf(val);
        }
      }
    }
  }
#undef STAGE_QKV
}

// per-head chunk offset table: off[qt] = sum_{j<qt} ceil((j+1)/4); off[16]=40
DEVI int chunk_off(int qt) {
  const int off[17] = {0,1,2,3,4,6,8,10,12,15,18,21,24,28,32,36,40};
  return off[qt];
}

// ---------------- flash attention partials: one block = (h, qt, chunk of <=4 K-tiles) ----------------
// Swapped QK^T (S^T = mfma(K, Q)) keeps P lane-local: lane (g,li) holds P[q=li][t2=cf*16+4g+r].
// PV uses a custom k-relabeling (k-slot (g,j) -> t2 = 32*ks2 + (j<4 ? 4g+j : 16+4g+j-4)) applied
// to BOTH operands, so packed P dwords feed the A-operand from own registers (no LDS, no shuffle);
// V pays 2x ds_read_b64 per fragment. K/V LDS tiles 16B-chunk XOR-swizzled via pre-swizzled
// global source (rule #21).
__global__ __launch_bounds__(256) void k_attn_part(
    const unsigned short* __restrict__ qs, const unsigned short* __restrict__ kbuf,
    const unsigned short* __restrict__ vT,
    float* __restrict__ o_part, float* __restrict__ ml) {
  __shared__ __align__(16) unsigned short Ks[128 * 64];   // [t2][d], swz &7
  __shared__ __align__(16) unsigned short Vs[64 * 128];   // [d][t2], swz &15
  const int lane = threadIdx.x & 63, wid = threadIdx.x >> 6;
  const int g = lane >> 4, li = lane & 15;

  // decode work unit
  const int h = blockIdx.x / 40;
  const int rem = blockIdx.x % 40;
  int qt = 0;
#pragma unroll
  for (int i = 0; i < 16; i++)
    if (rem >= chunk_off(i + 1)) qt = i + 1;
  const int ci = rem - chunk_off(qt);
  const int kt0 = ci * 4;
  const int kt1 = min(qt, kt0 + 3);
  const int q0 = qt * 128;

  const bf16x8 bzero = {0, 0, 0, 0, 0, 0, 0, 0};

  // Q fragments (B-operand): lane holds Q[q=li][d=g*8..+7]; wave owns rows [wid*32, wid*32+32)
  bf16x8 qf[2][2];
#pragma unroll
  for (int mi = 0; mi < 2; mi++)
#pragma unroll
    for (int ks = 0; ks < 2; ks++) {
      const int t = q0 + wid * 32 + mi * 16 + li;
      const int d = ks * 32 + g * 8;
      qf[mi][ks] = *reinterpret_cast<const bf16x8*>(qs + ((size_t)(h * 2048 + t) << 6) + d);
    }

  f32x4 o[2][4] = {};
  float m_run[2] = {-1e30f, -1e30f}, l_run[2] = {0.f, 0.f};

  const int q256 = qt >> 1;
  for (int kt = kt0; kt <= kt1; kt++) {
    __syncthreads();
    // stage K tile [128][64] and V tile [64][128]; source pre-swizzled so that
    // linear LDS dest holds chunk c of row r at slot c ^ (r & mask)
    for (int c = wid; c < 16; c += 4) {
      const int fb = c * 1024;
      const int flat = fb + lane * 16;
      {
        const int row = flat >> 7;
        const int cs = (((flat >> 4) & 7) ^ (row & 7)) << 4;
        g2l16((const char*)kbuf + (((size_t)(h * 2048 + kt * 128 + row)) << 7) + cs,
              (char*)Ks + fb);
      }
      {
        const int row = flat >> 8;
        const int cs = (((flat >> 4) & 15) ^ (row & 15)) << 4;
        g2l16((const char*)vT + ((size_t)(h * 64 + row) * 2048 + kt * 128) * 2 + cs,
              (char*)Vs + fb);
      }
    }
    __syncthreads();

    const int x = q256 ^ (kt >> 1);
    const int Keff = (x == 0) ? 64 : ((x >= 4) ? 32 : ((x >= 2) ? 48 : 56));

    // S^T = mfma(K, Q): st[cf][mi], lane (g,li): q = li, t2 = cf*16 + g*4 + r
    f32x4 st[8][2] = {};
#pragma unroll
    for (int cf = 0; cf < 8; cf++) {
      const int krow = cf * 16 + li;
      const bf16x8 a0 = *reinterpret_cast<const bf16x8*>(
          Ks + krow * 64 + ((g ^ (krow & 7)) << 3));
      st[cf][0] = __builtin_amdgcn_mfma_f32_16x16x32_bf16(a0, qf[0][0], st[cf][0], 0, 0, 0);
      st[cf][1] = __builtin_amdgcn_mfma_f32_16x16x32_bf16(a0, qf[1][0], st[cf][1], 0, 0, 0);
    }
    if (Keff > 32) {
      const bool zf = (32 + g * 8) >= Keff;
#pragma unroll
      for (int cf = 0; cf < 8; cf++) {
        const int krow = cf * 16 + li;
        bf16x8 a1 = *reinterpret_cast<const bf16x8*>(
            Ks + krow * 64 + (((4 + g) ^ (krow & 7)) << 3));
        if (zf) a1 = bzero;
        st[cf][0] = __builtin_amdgcn_mfma_f32_16x16x32_bf16(a1, qf[0][1], st[cf][0], 0, 0, 0);
        st[cf][1] = __builtin_amdgcn_mfma_f32_16x16x32_bf16(a1, qf[1][1], st[cf][1], 0, 0, 0);
      }
    }

    // causal mask on the diagonal tile: t2 > q
    if (kt == qt) {
#pragma unroll
      for (int cf = 0; cf < 8; cf++)
#pragma unroll
        for (int mi = 0; mi < 2; mi++)
#pragma unroll
          for (int r = 0; r < 4; r++) {
            const int t2 = cf * 16 + g * 4 + r;
            const int qq = wid * 32 + mi * 16 + li;
            if (t2 > qq) st[cf][mi][r] = -1e30f;
          }
    }

    // online softmax (row = q = li, in-lane over 32 t2 + cross-group xor16/32) + pack to bf16
    int pk[2][8][2];
    float corrb[2][4];
#pragma unroll
    for (int mi = 0; mi < 2; mi++) {
      float tm = st[0][mi][0];
#pragma unroll
      for (int cf = 0; cf < 8; cf++)
#pragma unroll
        for (int r = 0; r < 4; r++)
          if (cf | r) tm = fmaxf(tm, st[cf][mi][r]);
      tm = fmaxf(tm, __shfl_xor(tm, 16));
      tm = fmaxf(tm, __shfl_xor(tm, 32));
      const float mn = fmaxf(m_run[mi], tm);
      const float corr = __expf(m_run[mi] - mn);
      m_run[mi] = mn;
      float sum = 0.f;
#pragma unroll
      for (int cf = 0; cf < 8; cf++) {
        const float p0 = __expf(st[cf][mi][0] - mn);
        const float p1 = __expf(st[cf][mi][1] - mn);
        const float p2 = __expf(st[cf][mi][2] - mn);
        const float p3 = __expf(st[cf][mi][3] - mn);
        sum += (p0 + p1) + (p2 + p3);
        pk[mi][cf][0] = cvtpk(p0, p1);
        pk[mi][cf][1] = cvtpk(p2, p3);
      }
      sum += __shfl_xor(sum, 16);
      sum += __shfl_xor(sum, 32);
      l_run[mi] = l_run[mi] * corr + sum;
      // broadcast corr from softmax layout (q=li) to O layout (q=g*4+r)
      corrb[mi][0] = __shfl(corr, 4 * g + 0);
      corrb[mi][1] = __shfl(corr, 4 * g + 1);
      corrb[mi][2] = __shfl(corr, 4 * g + 2);
      corrb[mi][3] = __shfl(corr, 4 * g + 3);
    }
#pragma unroll
    for (int mi = 0; mi < 2; mi++)
#pragma unroll
      for (int nf = 0; nf < 4; nf++)
#pragma unroll
        for (int r = 0; r < 4; r++)
          o[mi][nf][r] *= corrb[mi][r];

    // O += P V with custom k-labeling; P from own registers, V via 2x b64 swizzled reads
#pragma unroll
    for (int ks2 = 0; ks2 < 4; ks2++) {
      bf16x8 pa[2];
#pragma unroll
      for (int mi = 0; mi < 2; mi++) {
        union { int i[4]; bf16x8 v; } u;
        u.i[0] = pk[mi][2 * ks2][0];
        u.i[1] = pk[mi][2 * ks2][1];
        u.i[2] = pk[mi][2 * ks2 + 1][0];
        u.i[3] = pk[mi][2 * ks2 + 1][1];
        pa[mi] = u.v;
      }
      bf16x8 vb[4];
#pragma unroll
      for (int nf = 0; nf < 4; nf++) {
        const int vrow = nf * 16 + li;
        const int rm = vrow & 15;
        const int ch0 = 4 * ks2 + (g >> 1);
        const int b8 = (g & 1) * 8;
        union { struct { int2 lo, hi; } p; bf16x8 v; } u;
        u.p.lo = *reinterpret_cast<const int2*>(
            (const char*)Vs + vrow * 256 + (((ch0 + 0) ^ rm) << 4) + b8);
        u.p.hi = *reinterpret_cast<const int2*>(
            (const char*)Vs + vrow * 256 + (((ch0 + 2) ^ rm) << 4) + b8);
        vb[nf] = u.v;
      }
#pragma unroll
      for (int mi = 0; mi < 2; mi++)
#pragma unroll
        for (int nf = 0; nf < 4; nf++)
          o[mi][nf] = __builtin_amdgcn_mfma_f32_16x16x32_bf16(pa[mi], vb[nf], o[mi][nf], 0, 0, 0);
    }
  }

  // write unnormalized partial O (fp32) + m,l
  const size_t pbase = (size_t)blockIdx.x * 8192;
#pragma unroll
  for (int mi = 0; mi < 2; mi++) {
#pragma unroll
    for (int nf = 0; nf < 4; nf++)
#pragma unroll
      for (int r = 0; r < 4; r++) {
        const int row = wid * 32 + mi * 16 + g * 4 + r;
        o_part[pbase + (size_t)row * 64 + nf * 16 + li] = o[mi][nf][r];
      }
  }
  if (g == 0) {
#pragma unroll
    for (int mi = 0; mi < 2; mi++) {
      const int row = wid * 32 + mi * 16 + li;
      ml[(size_t)blockIdx.x * 256 + row] = m_run[mi];
      ml[(size_t)blockIdx.x * 256 + 128 + row] = l_run[mi];
    }
  }
}

// ---------------- combine partials -> yb bf16 [t][h*64+d] ----------------
__global__ __launch_bounds__(256) void k_combine(
    const float* __restrict__ o_part, const float* __restrict__ ml,
    unsigned short* __restrict__ yb) {
  const int h = blockIdx.x >> 4, qt = blockIdx.x & 15;
  const int nc = (qt >> 2) + 1;
  const int base = h * 40 + chunk_off(qt);
  const int row = threadIdx.x >> 1;
  const int c0 = (threadIdx.x & 1) * 32;

  float m_i[4], l_i[4];
  float M = -1e30f;
  for (int ci = 0; ci < nc; ci++) {
    m_i[ci] = ml[(size_t)(base + ci) * 256 + row];
    l_i[ci] = ml[(size_t)(base + ci) * 256 + 128 + row];
    M = fmaxf(M, m_i[ci]);
  }
  float L = 0.f, w[4];
  for (int ci = 0; ci < nc; ci++) {
    w[ci] = __expf(m_i[ci] - M);
    L += w[ci] * l_i[ci];
  }
  const float inv = 1.0f / L;

  float acc[32];
#pragma unroll
  for (int j = 0; j < 32; j++) acc[j] = 0.f;
  for (int ci = 0; ci < nc; ci++) {
    const float* src = o_part + (size_t)(base + ci) * 8192 + (size_t)row * 64 + c0;
    const float wc = w[ci];
#pragma unroll
    for (int j4 = 0; j4 < 8; j4++) {
      float4 v = reinterpret_cast<const float4*>(src)[j4];
      acc[j4 * 4 + 0] += wc * v.x;
      acc[j4 * 4 + 1] += wc * v.y;
      acc[j4 * 4 + 2] += wc * v.z;
      acc[j4 * 4 + 3] += wc * v.w;
    }
  }
  const int t = qt * 128 + row;
  unsigned short* dst = yb + (size_t)t * 1024 + h * 64 + c0;
#pragma unroll
  for (int j8 = 0; j8 < 4; j8++) {
    ushort4 pk;
    pk.x = f2bf(acc[j8 * 8 + 0] * inv);
    pk.y = f2bf(acc[j8 * 8 + 1] * inv);
    pk.z = f2bf(acc[j8 * 8 + 2] * inv);
    pk.w = f2bf(acc[j8 * 8 + 3] * inv);
    ushort4 pk2;
    pk2.x = f2bf(acc[j8 * 8 + 4] * inv);
    pk2.y = f2bf(acc[j8 * 8 + 5] * inv);
    pk2.z = f2bf(acc[j8 * 8 + 6] * inv);
    pk2.w = f2bf(acc[j8 * 8 + 7] * inv);
    reinterpret_cast<ushort4*>(dst)[j8 * 2 + 0] = pk;
    reinterpret_cast<ushort4*>(dst)[j8 * 2 + 1] = pk2;
  }
}

// ---------------- proj GEMM: 64x64 tile, 2-phase dbuf pipeline -> fp32 out + bias ----------------
// grid (16, 32): x = n-tile, y = m-tile. 512 blocks.
__global__ __launch_bounds__(256) void k_gemm_proj(
    const unsigned short* __restrict__ A, const unsigned short* __restrict__ Bt,
    const float* __restrict__ bias, float* __restrict__ out) {
  constexpr int K = 1024;
  __shared__ __align__(16) unsigned short As[2][64 * 64];
  __shared__ __align__(16) unsigned short Bs[2][64 * 64];
  const int lane = threadIdx.x & 63, wid = threadIdx.x >> 6;
  const int m0 = blockIdx.y * 64, n0 = blockIdx.x * 64;
  const int wr = (wid >> 1) * 32, wc = (wid & 1) * 32;
  const int g = lane >> 4, li = lane & 15;
  f32x4 acc[2][2] = {};

#define STAGE_PROJ(buf, k0)                                                             \
  {                                                                                     \
    _Pragma("unroll")                                                                   \
    for (int c = wid * 2; c < wid * 2 + 2; c++) {                                       \
      const int flat = c * 1024 + lane * 16;                                            \
      const int row = flat >> 7, colb = flat & 127;                                     \
      g2l16((const char*)A + ((size_t)(m0 + row) * K + (k0)) * 2 + colb,                \
            (char*)As[buf] + c * 1024);                                                 \
      g2l16((const char*)Bt + ((size_t)(n0 + row) * K + (k0)) * 2 + colb,               \
            (char*)Bs[buf] + c * 1024);                                                 \
    }                                                                                   \
  }

  STAGE_PROJ(0, 0);
  __syncthreads();
  int buf = 0;
  for (int t = 0; t < 16; t++) {
    if (t < 15) STAGE_PROJ(buf ^ 1, (t + 1) * 64);
#pragma unroll
    for (int ks = 0; ks < 2; ks++) {
      const int kk = ks * 32 + g * 8;
      bf16x8 a[2], b[2];
#pragma unroll
      for (int i = 0; i < 2; i++)
        a[i] = *reinterpret_cast<const bf16x8*>(As[buf] + (wr + i * 16 + li) * 64 + kk);
#pragma unroll
      for (int j = 0; j < 2; j++)
        b[j] = *reinterpret_cast<const bf16x8*>(Bs[buf] + (wc + j * 16 + li) * 64 + kk);
#pragma unroll
      for (int i = 0; i < 2; i++)
#pragma unroll
        for (int j = 0; j < 2; j++)
          acc[i][j] = __builtin_amdgcn_mfma_f32_16x16x32_bf16(a[i], b[j], acc[i][j], 0, 0, 0);
    }
    __syncthreads();
    buf ^= 1;
  }

  const int rb = m0 + wr + g * 4;
  const int cb = n0 + wc + li;
#pragma unroll
  for (int j = 0; j < 2; j++) {
    const int c = cb + j * 16;
    const float bv = bias[c];
#pragma unroll
    for (int i = 0; i < 2; i++) {
#pragma unroll
      for (int r = 0; r < 4; r++) {
        const int t = rb + i * 16 + r;
        out[(size_t)t * 1024 + c] = acc[i][j][r] + bv;
      }
    }
  }
#undef STAGE_PROJ
}

extern "C" void kernel_launch(void* const* d_in, const int* in_sizes, int n_in,
                              void* d_out, int out_size, void* d_ws, size_t ws_size,
                              hipStream_t stream) {
  const float* x      = (const float*)d_in[0];
  const float* W_attn = (const float*)d_in[1];
  const float* b_attn = (const float*)d_in[2];
  const float* W_proj = (const float*)d_in[3];
  const float* b_proj = (const float*)d_in[4];
  float* out = (float*)d_out;
  char* ws = (char*)d_ws;
  const size_t MB = 1024 * 1024;
  unsigned short* xb  = (unsigned short*)(ws + 0 * MB);   // [2048][1024] bf16
  unsigned short* WaT = (unsigned short*)(ws + 4 * MB);   // [3072][1024] bf16
  unsigned short* WpT = (unsigned short*)(ws + 10 * MB);  // [1024][1024] bf16
  unsigned short* qs  = (unsigned short*)(ws + 12 * MB);  // [16][2048][64] bf16, pre-scaled
  unsigned short* kb  = (unsigned short*)(ws + 16 * MB);  // [16][2048][64] bf16
  unsigned short* vT  = (unsigned short*)(ws + 20 * MB);  // [16][64][2048] bf16
  unsigned short* yb  = (unsigned short*)(ws + 24 * MB);  // [2048][1024] bf16
  float* o_part = (float*)(ws + 28 * MB);                 // [640][128][64] fp32 (20 MB)
  float* ml     = (float*)(ws + 48 * MB + 256 * 1024);    // [640][2][128] fp32

  k_convx<<<dim3(2048), dim3(256), 0, stream>>>(x, xb, 524288);
  k_tconv<<<dim3(96, 32), dim3(32, 8), 0, stream>>>(W_attn, WaT, 1024, 3072);
  k_tconv<<<dim3(32, 32), dim3(32, 8), 0, stream>>>(W_proj, WpT, 1024, 1024);
  k_gemm_qkv<<<dim3(48, 16), dim3(256), 0, stream>>>(xb, WaT, b_attn, qs, kb, vT);
  k_attn_part<<<dim3(640), dim3(256), 0, stream>>>(qs, kb, vT, o_part, ml);
  k_combine<<<dim3(256), dim3(256), 0, stream>>>(o_part, ml, yb);
  k_gemm_proj<<<dim3(16, 32), dim3(256), 0, stream>>>(yb, WpT, b_proj, out);
}

// Round 6
// 96.517 us; speedup vs baseline: 1.4048x; 1.0749x over previous
//
#include <hip/hip_runtime.h>

using bf16x8 = __attribute__((ext_vector_type(8))) short;
using u16x8  = __attribute__((ext_vector_type(8))) unsigned short;
using f32x4  = __attribute__((ext_vector_type(4))) float;

#define DEVI __device__ __forceinline__

// round-to-nearest-even fp32 -> bf16 (bit pattern)
DEVI unsigned short f2bf(float f) {
  union { float ff; unsigned u; } v; v.ff = f;
  unsigned r = v.u + 0x7FFFu + ((v.u >> 16) & 1u);
  return (unsigned short)(r >> 16);
}

DEVI float bf2f(unsigned short s) {
  union { unsigned u; float f; } t; t.u = ((unsigned)s) << 16;
  return t.f;
}

// pack two f32 -> one dword of 2 bf16 (RNE), low = lo, high = hi
DEVI int cvtpk(float lo, float hi) {
  int r;
  asm("v_cvt_pk_bf16_f32 %0, %1, %2" : "=v"(r) : "v"(lo), "v"(hi));
  return r;
}

// async global->LDS, 16B per lane; l must be wave-uniform base (HW adds lane*16)
DEVI void g2l16(const void* g, void* l) {
  __builtin_amdgcn_global_load_lds(
      (const __attribute__((address_space(1))) unsigned int*)g,
      (__attribute__((address_space(3))) unsigned int*)l, 16, 0, 0);
}

// ---------------- prep: x fp32->bf16, W_attn / W_proj transpose+convert ----------------
// grid 6144: [0,2048) convx, [2048,5120) tconv W_attn (96x32), [5120,6144) tconv W_proj (32x32)
__global__ __launch_bounds__(256) void k_prep(
    const float* __restrict__ x, const float* __restrict__ Wa, const float* __restrict__ Wp,
    unsigned short* __restrict__ xb, unsigned short* __restrict__ WaT,
    unsigned short* __restrict__ WpT) {
  __shared__ float tile[32][33];
  const int b = blockIdx.x;
  const int tid = threadIdx.x;
  if (b < 2048) {
    const int i = b * 256 + tid;
    float4 v = reinterpret_cast<const float4*>(x)[i];
    ushort4 o;
    o.x = f2bf(v.x); o.y = f2bf(v.y); o.z = f2bf(v.z); o.w = f2bf(v.w);
    reinterpret_cast<ushort4*>(xb)[i] = o;
    return;
  }
  const float* in;
  unsigned short* out;
  int c0, r0, C;
  if (b < 5120) {
    const int bb = b - 2048;
    in = Wa; out = WaT; C = 3072;
    c0 = (bb % 96) * 32; r0 = (bb / 96) * 32;
  } else {
    const int bb = b - 5120;
    in = Wp; out = WpT; C = 1024;
    c0 = (bb & 31) * 32; r0 = (bb >> 5) * 32;
  }
  const int xx = tid & 31, yy = tid >> 5;
  for (int i = yy; i < 32; i += 8) tile[i][xx] = in[(size_t)(r0 + i) * C + c0 + xx];
  __syncthreads();
  for (int i = yy; i < 32; i += 8) out[(size_t)(c0 + i) * 1024 + r0 + xx] = f2bf(tile[xx][i]);
}

// ---------------- QKV GEMM: 128x64 tile, 2-phase dbuf pipeline ----------------
// grid (48, 16): x = n-tile (64 cols), y = m-tile (128 rows). 768 blocks.
__global__ __launch_bounds__(256) void k_gemm_qkv(
    const unsigned short* __restrict__ A, const unsigned short* __restrict__ Bt,
    const float* __restrict__ bias,
    unsigned short* __restrict__ qs, unsigned short* __restrict__ kbuf,
    unsigned short* __restrict__ vT) {
  constexpr int K = 1024;
  __shared__ __align__(16) unsigned short As[2][128 * 64];
  __shared__ __align__(16) unsigned short Bs[2][64 * 64];
  const int lane = threadIdx.x & 63, wid = threadIdx.x >> 6;
  const int m0 = blockIdx.y * 128, n0 = blockIdx.x * 64;
  const int wr = (wid >> 1) * 64, wc = (wid & 1) * 32;
  const int g = lane >> 4, li = lane & 15;
  f32x4 acc[4][2] = {};

#define STAGE_QKV(buf, k0)                                                              \
  {                                                                                     \
    _Pragma("unroll")                                                                   \
    for (int c = wid * 4; c < wid * 4 + 4; c++) {                                       \
      const int flat = c * 1024 + lane * 16;                                            \
      const int row = flat >> 7, colb = flat & 127;                                     \
      g2l16((const char*)A + ((size_t)(m0 + row) * K + (k0)) * 2 + colb,                \
            (char*)As[buf] + c * 1024);                                                 \
    }                                                                                   \
    _Pragma("unroll")                                                                   \
    for (int c = wid * 2; c < wid * 2 + 2; c++) {                                       \
      const int flat = c * 1024 + lane * 16;                                            \
      const int row = flat >> 7, colb = flat & 127;                                     \
      g2l16((const char*)Bt + ((size_t)(n0 + row) * K + (k0)) * 2 + colb,               \
            (char*)Bs[buf] + c * 1024);                                                 \
    }                                                                                   \
  }

  STAGE_QKV(0, 0);
  __syncthreads();
  int buf = 0;
  for (int t = 0; t < 16; t++) {
    if (t < 15) STAGE_QKV(buf ^ 1, (t + 1) * 64);
#pragma unroll
    for (int ks = 0; ks < 2; ks++) {
      const int kk = ks * 32 + g * 8;
      bf16x8 a[4], b[2];
#pragma unroll
      for (int i = 0; i < 4; i++)
        a[i] = *reinterpret_cast<const bf16x8*>(As[buf] + (wr + i * 16 + li) * 64 + kk);
#pragma unroll
      for (int j = 0; j < 2; j++)
        b[j] = *reinterpret_cast<const bf16x8*>(Bs[buf] + (wc + j * 16 + li) * 64 + kk);
#pragma unroll
      for (int i = 0; i < 4; i++)
#pragma unroll
        for (int j = 0; j < 2; j++)
          acc[i][j] = __builtin_amdgcn_mfma_f32_16x16x32_bf16(a[i], b[j], acc[i][j], 0, 0, 0);
    }
    __syncthreads();
    buf ^= 1;
  }

  const int rb = m0 + wr + g * 4;
  const int cb = n0 + wc + li;
#pragma unroll
  for (int j = 0; j < 2; j++) {
    const int c = cb + j * 16;
    const float bv = bias[c];
    const int hq = c >> 6, d = c & 63;
    const float sc = d < 32 ? 0.03125f : (d < 48 ? 0.0625f : 0.125f);
#pragma unroll
    for (int i = 0; i < 4; i++) {
#pragma unroll
      for (int r = 0; r < 4; r++) {
        const int t = rb + i * 16 + r;
        const float val = acc[i][j][r] + bv;
        if (c < 1024) {
          qs[((size_t)(hq * 2048 + t) << 6) + d] = f2bf(val * sc);
        } else if (c < 2048) {
          kbuf[((size_t)((hq - 16) * 2048 + t) << 6) + d] = f2bf(val);
        } else {
          vT[(size_t)((hq - 32) * 64 + d) * 2048 + t] = f2bf(val);
        }
      }
    }
  }
#undef STAGE_QKV
}

// per-head chunk offset table: off[qt] = sum_{j<qt} ceil((j+1)/4); off[16]=40
DEVI int chunk_off(int qt) {
  const int off[17] = {0,1,2,3,4,6,8,10,12,15,18,21,24,28,32,36,40};
  return off[qt];
}

// ---------------- flash attention partials: one block = (h, qt, chunk of <=4 K-tiles) ----------------
// Swapped QK^T keeps P lane-local; PV feeds packed P from own registers (see R3 notes).
// K/V double-buffered in LDS (64 KB): one barrier per tile; next tile's global_load_lds
// issued before current tile's compute, drained by next barrier's implicit vmcnt(0).
__global__ __launch_bounds__(256) void k_attn_part(
    const unsigned short* __restrict__ qs, const unsigned short* __restrict__ kbuf,
    const unsigned short* __restrict__ vT,
    unsigned short* __restrict__ o_part, float* __restrict__ ml) {
  __shared__ __align__(16) unsigned short Ks[2][128 * 64];   // [t2][d], swz &7
  __shared__ __align__(16) unsigned short Vs[2][64 * 128];   // [d][t2], swz &15
  const int lane = threadIdx.x & 63, wid = threadIdx.x >> 6;
  const int g = lane >> 4, li = lane & 15;

  // decode work unit
  const int h = blockIdx.x / 40;
  const int rem = blockIdx.x % 40;
  int qt = 0;
#pragma unroll
  for (int i = 0; i < 16; i++)
    if (rem >= chunk_off(i + 1)) qt = i + 1;
  const int ci = rem - chunk_off(qt);
  const int kt0 = ci * 4;
  const int kt1 = min(qt, kt0 + 3);
  const int q0 = qt * 128;

  const bf16x8 bzero = {0, 0, 0, 0, 0, 0, 0, 0};

#define STAGE_KV(buf, kt)                                                               \
  for (int c = wid; c < 16; c += 4) {                                                   \
    const int fb = c * 1024;                                                            \
    const int flat = fb + lane * 16;                                                    \
    {                                                                                   \
      const int row = flat >> 7;                                                        \
      const int cs = (((flat >> 4) & 7) ^ (row & 7)) << 4;                              \
      g2l16((const char*)kbuf + (((size_t)(h * 2048 + (kt) * 128 + row)) << 7) + cs,    \
            (char*)Ks[buf] + fb);                                                       \
    }                                                                                   \
    {                                                                                   \
      const int row = flat >> 8;                                                        \
      const int cs = (((flat >> 4) & 15) ^ (row & 15)) << 4;                            \
      g2l16((const char*)vT + ((size_t)(h * 64 + row) * 2048 + (kt) * 128) * 2 + cs,    \
            (char*)Vs[buf] + fb);                                                       \
    }                                                                                   \
  }

  // Q fragments (B-operand): lane holds Q[q=li][d=g*8..+7]; wave owns rows [wid*32, wid*32+32)
  bf16x8 qf[2][2];
#pragma unroll
  for (int mi = 0; mi < 2; mi++)
#pragma unroll
    for (int ks = 0; ks < 2; ks++) {
      const int t = q0 + wid * 32 + mi * 16 + li;
      const int d = ks * 32 + g * 8;
      qf[mi][ks] = *reinterpret_cast<const bf16x8*>(qs + ((size_t)(h * 2048 + t) << 6) + d);
    }

  f32x4 o[2][4] = {};
  float m_run[2] = {-1e30f, -1e30f}, l_run[2] = {0.f, 0.f};

  const int q256 = qt >> 1;
  STAGE_KV(0, kt0);
  int buf = 0;
  for (int kt = kt0; kt <= kt1; kt++) {
    __syncthreads();   // drains stage into buf (implicit vmcnt(0)), fences prior reads
    if (kt < kt1) STAGE_KV(buf ^ 1, kt + 1);

    const int x = q256 ^ (kt >> 1);
    const int Keff = (x == 0) ? 64 : ((x >= 4) ? 32 : ((x >= 2) ? 48 : 56));

    // S^T = mfma(K, Q): st[cf][mi], lane (g,li): q = li, t2 = cf*16 + g*4 + r
    f32x4 st[8][2] = {};
    __builtin_amdgcn_s_setprio(1);
#pragma unroll
    for (int cf = 0; cf < 8; cf++) {
      const int krow = cf * 16 + li;
      const bf16x8 a0 = *reinterpret_cast<const bf16x8*>(
          Ks[buf] + krow * 64 + ((g ^ (krow & 7)) << 3));
      st[cf][0] = __builtin_amdgcn_mfma_f32_16x16x32_bf16(a0, qf[0][0], st[cf][0], 0, 0, 0);
      st[cf][1] = __builtin_amdgcn_mfma_f32_16x16x32_bf16(a0, qf[1][0], st[cf][1], 0, 0, 0);
    }
    if (Keff > 32) {
      const bool zf = (32 + g * 8) >= Keff;
#pragma unroll
      for (int cf = 0; cf < 8; cf++) {
        const int krow = cf * 16 + li;
        bf16x8 a1 = *reinterpret_cast<const bf16x8*>(
            Ks[buf] + krow * 64 + (((4 + g) ^ (krow & 7)) << 3));
        if (zf) a1 = bzero;
        st[cf][0] = __builtin_amdgcn_mfma_f32_16x16x32_bf16(a1, qf[0][1], st[cf][0], 0, 0, 0);
        st[cf][1] = __builtin_amdgcn_mfma_f32_16x16x32_bf16(a1, qf[1][1], st[cf][1], 0, 0, 0);
      }
    }
    __builtin_amdgcn_s_setprio(0);

    // causal mask on the diagonal tile: t2 > q
    if (kt == qt) {
#pragma unroll
      for (int cf = 0; cf < 8; cf++)
#pragma unroll
        for (int mi = 0; mi < 2; mi++)
#pragma unroll
          for (int r = 0; r < 4; r++) {
            const int t2 = cf * 16 + g * 4 + r;
            const int qq = wid * 32 + mi * 16 + li;
            if (t2 > qq) st[cf][mi][r] = -1e30f;
          }
    }

    // online softmax (row = q = li): balanced max tree + in-lane exp, pack to bf16
    int pk[2][8][2];
    float corrb[2][4];
#pragma unroll
    for (int mi = 0; mi < 2; mi++) {
      float c4[8];
#pragma unroll
      for (int cf = 0; cf < 8; cf++)
        c4[cf] = fmaxf(fmaxf(st[cf][mi][0], st[cf][mi][1]),
                       fmaxf(st[cf][mi][2], st[cf][mi][3]));
      const float ta = fmaxf(fmaxf(c4[0], c4[1]), fmaxf(c4[2], c4[3]));
      const float tb = fmaxf(fmaxf(c4[4], c4[5]), fmaxf(c4[6], c4[7]));
      float tm = fmaxf(ta, tb);
      tm = fmaxf(tm, __shfl_xor(tm, 16));
      tm = fmaxf(tm, __shfl_xor(tm, 32));
      const float mn = fmaxf(m_run[mi], tm);
      const float corr = __expf(m_run[mi] - mn);
      m_run[mi] = mn;
      float sum = 0.f;
#pragma unroll
      for (int cf = 0; cf < 8; cf++) {
        const float p0 = __expf(st[cf][mi][0] - mn);
        const float p1 = __expf(st[cf][mi][1] - mn);
        const float p2 = __expf(st[cf][mi][2] - mn);
        const float p3 = __expf(st[cf][mi][3] - mn);
        sum += (p0 + p1) + (p2 + p3);
        pk[mi][cf][0] = cvtpk(p0, p1);
        pk[mi][cf][1] = cvtpk(p2, p3);
      }
      sum += __shfl_xor(sum, 16);
      sum += __shfl_xor(sum, 32);
      l_run[mi] = l_run[mi] * corr + sum;
      // broadcast corr from softmax layout (q=li) to O layout (q=g*4+r)
      corrb[mi][0] = __shfl(corr, 4 * g + 0);
      corrb[mi][1] = __shfl(corr, 4 * g + 1);
      corrb[mi][2] = __shfl(corr, 4 * g + 2);
      corrb[mi][3] = __shfl(corr, 4 * g + 3);
    }
#pragma unroll
    for (int mi = 0; mi < 2; mi++)
#pragma unroll
      for (int nf = 0; nf < 4; nf++)
#pragma unroll
        for (int r = 0; r < 4; r++)
          o[mi][nf][r] *= corrb[mi][r];

    // O += P V with custom k-labeling; P from own registers, V via 2x b64 swizzled reads
    __builtin_amdgcn_s_setprio(1);
#pragma unroll
    for (int ks2 = 0; ks2 < 4; ks2++) {
      bf16x8 pa[2];
#pragma unroll
      for (int mi = 0; mi < 2; mi++) {
        union { int i[4]; bf16x8 v; } u;
        u.i[0] = pk[mi][2 * ks2][0];
        u.i[1] = pk[mi][2 * ks2][1];
        u.i[2] = pk[mi][2 * ks2 + 1][0];
        u.i[3] = pk[mi][2 * ks2 + 1][1];
        pa[mi] = u.v;
      }
      bf16x8 vb[4];
#pragma unroll
      for (int nf = 0; nf < 4; nf++) {
        const int vrow = nf * 16 + li;
        const int rm = vrow & 15;
        const int ch0 = 4 * ks2 + (g >> 1);
        const int b8 = (g & 1) * 8;
        union { struct { int2 lo, hi; } p; bf16x8 v; } u;
        u.p.lo = *reinterpret_cast<const int2*>(
            (const char*)Vs[buf] + vrow * 256 + (((ch0 + 0) ^ rm) << 4) + b8);
        u.p.hi = *reinterpret_cast<const int2*>(
            (const char*)Vs[buf] + vrow * 256 + (((ch0 + 2) ^ rm) << 4) + b8);
        vb[nf] = u.v;
      }
#pragma unroll
      for (int mi = 0; mi < 2; mi++)
#pragma unroll
        for (int nf = 0; nf < 4; nf++)
          o[mi][nf] = __builtin_amdgcn_mfma_f32_16x16x32_bf16(pa[mi], vb[nf], o[mi][nf], 0, 0, 0);
    }
    __builtin_amdgcn_s_setprio(0);
    buf ^= 1;
  }
#undef STAGE_KV

  // write unnormalized partial O (bf16) + m,l (fp32)
  const size_t pbase = (size_t)blockIdx.x * 8192;
#pragma unroll
  for (int mi = 0; mi < 2; mi++) {
#pragma unroll
    for (int nf = 0; nf < 4; nf++)
#pragma unroll
      for (int r = 0; r < 4; r++) {
        const int row = wid * 32 + mi * 16 + g * 4 + r;
        o_part[pbase + (size_t)row * 64 + nf * 16 + li] = f2bf(o[mi][nf][r]);
      }
  }
  if (g == 0) {
#pragma unroll
    for (int mi = 0; mi < 2; mi++) {
      const int row = wid * 32 + mi * 16 + li;
      ml[(size_t)blockIdx.x * 256 + row] = m_run[mi];
      ml[(size_t)blockIdx.x * 256 + 128 + row] = l_run[mi];
    }
  }
}

// ---------------- combine partials (bf16) -> yb bf16 [t][h*64+d] ----------------
__global__ __launch_bounds__(256) void k_combine(
    const unsigned short* __restrict__ o_part, const float* __restrict__ ml,
    unsigned short* __restrict__ yb) {
  const int h = blockIdx.x >> 4, qt = blockIdx.x & 15;
  const int nc = (qt >> 2) + 1;
  const int base = h * 40 + chunk_off(qt);
  const int row = threadIdx.x >> 1;
  const int c0 = (threadIdx.x & 1) * 32;

  float m_i[4], l_i[4];
  float M = -1e30f;
  for (int ci = 0; ci < nc; ci++) {
    m_i[ci] = ml[(size_t)(base + ci) * 256 + row];
    l_i[ci] = ml[(size_t)(base + ci) * 256 + 128 + row];
    M = fmaxf(M, m_i[ci]);
  }
  float L = 0.f, w[4];
  for (int ci = 0; ci < nc; ci++) {
    w[ci] = __expf(m_i[ci] - M);
    L += w[ci] * l_i[ci];
  }
  const float inv = 1.0f / L;

  float acc[32];
#pragma unroll
  for (int j = 0; j < 32; j++) acc[j] = 0.f;
  for (int ci = 0; ci < nc; ci++) {
    const u16x8* src = reinterpret_cast<const u16x8*>(
        o_part + (size_t)(base + ci) * 8192 + (size_t)row * 64 + c0);
    const float wc = w[ci];
#pragma unroll
    for (int j8 = 0; j8 < 4; j8++) {
      u16x8 v = src[j8];
#pragma unroll
      for (int e = 0; e < 8; e++) acc[j8 * 8 + e] += wc * bf2f(v[e]);
    }
  }
  const int t = qt * 128 + row;
  unsigned short* dst = yb + (size_t)t * 1024 + h * 64 + c0;
#pragma unroll
  for (int j8 = 0; j8 < 4; j8++) {
    ushort4 pk;
    pk.x = f2bf(acc[j8 * 8 + 0] * inv);
    pk.y = f2bf(acc[j8 * 8 + 1] * inv);
    pk.z = f2bf(acc[j8 * 8 + 2] * inv);
    pk.w = f2bf(acc[j8 * 8 + 3] * inv);
    ushort4 pk2;
    pk2.x = f2bf(acc[j8 * 8 + 4] * inv);
    pk2.y = f2bf(acc[j8 * 8 + 5] * inv);
    pk2.z = f2bf(acc[j8 * 8 + 6] * inv);
    pk2.w = f2bf(acc[j8 * 8 + 7] * inv);
    reinterpret_cast<ushort4*>(dst)[j8 * 2 + 0] = pk;
    reinterpret_cast<ushort4*>(dst)[j8 * 2 + 1] = pk2;
  }
}

// ---------------- proj GEMM: 64x64 tile, 2-phase dbuf pipeline -> fp32 out + bias ----------------
// grid (16, 32): x = n-tile, y = m-tile. 512 blocks.
__global__ __launch_bounds__(256) void k_gemm_proj(
    const unsigned short* __restrict__ A, const unsigned short* __restrict__ Bt,
    const float* __restrict__ bias, float* __restrict__ out) {
  constexpr int K = 1024;
  __shared__ __align__(16) unsigned short As[2][64 * 64];
  __shared__ __align__(16) unsigned short Bs[2][64 * 64];
  const int lane = threadIdx.x & 63, wid = threadIdx.x >> 6;
  const int m0 = blockIdx.y * 64, n0 = blockIdx.x * 64;
  const int wr = (wid >> 1) * 32, wc = (wid & 1) * 32;
  const int g = lane >> 4, li = lane & 15;
  f32x4 acc[2][2] = {};

#define STAGE_PROJ(buf, k0)                                                             \
  {                                                                                     \
    _Pragma("unroll")                                                                   \
    for (int c = wid * 2; c < wid * 2 + 2; c++) {                                       \
      const int flat = c * 1024 + lane * 16;                                            \
      const int row = flat >> 7, colb = flat & 127;                                     \
      g2l16((const char*)A + ((size_t)(m0 + row) * K + (k0)) * 2 + colb,                \
            (char*)As[buf] + c * 1024);                                                 \
      g2l16((const char*)Bt + ((size_t)(n0 + row) * K + (k0)) * 2 + colb,               \
            (char*)Bs[buf] + c * 1024);                                                 \
    }                                                                                   \
  }

  STAGE_PROJ(0, 0);
  __syncthreads();
  int buf = 0;
  for (int t = 0; t < 16; t++) {
    if (t < 15) STAGE_PROJ(buf ^ 1, (t + 1) * 64);
#pragma unroll
    for (int ks = 0; ks < 2; ks++) {
      const int kk = ks * 32 + g * 8;
      bf16x8 a[2], b[2];
#pragma unroll
      for (int i = 0; i < 2; i++)
        a[i] = *reinterpret_cast<const bf16x8*>(As[buf] + (wr + i * 16 + li) * 64 + kk);
#pragma unroll
      for (int j = 0; j < 2; j++)
        b[j] = *reinterpret_cast<const bf16x8*>(Bs[buf] + (wc + j * 16 + li) * 64 + kk);
#pragma unroll
      for (int i = 0; i < 2; i++)
#pragma unroll
        for (int j = 0; j < 2; j++)
          acc[i][j] = __builtin_amdgcn_mfma_f32_16x16x32_bf16(a[i], b[j], acc[i][j], 0, 0, 0);
    }
    __syncthreads();
    buf ^= 1;
  }

  const int rb = m0 + wr + g * 4;
  const int cb = n0 + wc + li;
#pragma unroll
  for (int j = 0; j < 2; j++) {
    const int c = cb + j * 16;
    const float bv = bias[c];
#pragma unroll
    for (int i = 0; i < 2; i++) {
#pragma unroll
      for (int r = 0; r < 4; r++) {
        const int t = rb + i * 16 + r;
        out[(size_t)t * 1024 + c] = acc[i][j][r] + bv;
      }
    }
  }
#undef STAGE_PROJ
}

extern "C" void kernel_launch(void* const* d_in, const int* in_sizes, int n_in,
                              void* d_out, int out_size, void* d_ws, size_t ws_size,
                              hipStream_t stream) {
  const float* x      = (const float*)d_in[0];
  const float* W_attn = (const float*)d_in[1];
  const float* b_attn = (const float*)d_in[2];
  const float* W_proj = (const float*)d_in[3];
  const float* b_proj = (const float*)d_in[4];
  float* out = (float*)d_out;
  char* ws = (char*)d_ws;
  const size_t MB = 1024 * 1024;
  unsigned short* xb  = (unsigned short*)(ws + 0 * MB);   // [2048][1024] bf16
  unsigned short* WaT = (unsigned short*)(ws + 4 * MB);   // [3072][1024] bf16
  unsigned short* WpT = (unsigned short*)(ws + 10 * MB);  // [1024][1024] bf16
  unsigned short* qs  = (unsigned short*)(ws + 12 * MB);  // [16][2048][64] bf16, pre-scaled
  unsigned short* kb  = (unsigned short*)(ws + 16 * MB);  // [16][2048][64] bf16
  unsigned short* vT  = (unsigned short*)(ws + 20 * MB);  // [16][64][2048] bf16
  unsigned short* yb  = (unsigned short*)(ws + 24 * MB);  // [2048][1024] bf16
  unsigned short* o_part = (unsigned short*)(ws + 28 * MB); // [640][128][64] bf16 (10.5 MB)
  float* ml     = (float*)(ws + 39 * MB);                 // [640][2][128] fp32

  k_prep<<<dim3(6144), dim3(256), 0, stream>>>(x, W_attn, W_proj, xb, WaT, WpT);
  k_gemm_qkv<<<dim3(48, 16), dim3(256), 0, stream>>>(xb, WaT, b_attn, qs, kb, vT);
  k_attn_part<<<dim3(640), dim3(256), 0, stream>>>(qs, kb, vT, o_part, ml);
  k_combine<<<dim3(256), dim3(256), 0, stream>>>(o_part, ml, yb);
  k_gemm_proj<<<dim3(16, 32), dim3(256), 0, stream>>>(yb, WpT, b_proj, out);
}